// Round 14
// baseline (1437.669 us; speedup 1.0000x reference)
//
#include <hip/hip_runtime.h>
#include <hip/hip_bf16.h>
#include <math.h>

#define NODES 100000
#define EDGES 1200000
#define NG 256

typedef unsigned short u16;
typedef unsigned int   u32;
typedef __attribute__((ext_vector_type(8))) short bf16x8;
typedef __attribute__((ext_vector_type(4))) float f32x4;

__device__ __forceinline__ u16 f2bf(float f){
  u32 u = __float_as_uint(f);
  u32 r = (u + 0x7FFFu + ((u >> 16) & 1u)) >> 16;
  return (u16)r;
}
__device__ __forceinline__ float bf2f(u16 b){ return __uint_as_float(((u32)b) << 16); }
__device__ __forceinline__ float bfL(u32 v){ return __uint_as_float(v << 16); }
__device__ __forceinline__ float bfH(u32 v){ return __uint_as_float(v & 0xFFFF0000u); }
__device__ __forceinline__ u32 pk2(float a, float b){ return (u32)f2bf(a) | ((u32)f2bf(b) << 16); }

// ---------------- utility ----------------
__device__ __forceinline__ float wsum64(float v){
  v += __shfl_xor(v, 32); v += __shfl_xor(v, 16); v += __shfl_xor(v, 8);
  v += __shfl_xor(v, 4);  v += __shfl_xor(v, 2);  v += __shfl_xor(v, 1);
  return v;
}
__device__ __forceinline__ float wmax64(float v){
  v = fmaxf(v, __shfl_xor(v, 32)); v = fmaxf(v, __shfl_xor(v, 16));
  v = fmaxf(v, __shfl_xor(v, 8));  v = fmaxf(v, __shfl_xor(v, 4));
  v = fmaxf(v, __shfl_xor(v, 2));  v = fmaxf(v, __shfl_xor(v, 1));
  return v;
}
__device__ __forceinline__ float bsum256(float v, float* red){
  v = wsum64(v);
  if ((threadIdx.x & 63) == 0) red[threadIdx.x >> 6] = v;
  __syncthreads();
  float r = red[0] + red[1] + red[2] + red[3];
  __syncthreads();
  return r;
}

// ---------------- init: zero + ALL weight pre-transposes/conversions to bf16 ----------------
__global__ void k_init(int* counts, float* pooled,
                       const float* __restrict__ m1W, const float* __restrict__ m2W,
                       u16* __restrict__ w1t_g, u16* __restrict__ w2t_g,
                       const float* __restrict__ outW, const float* __restrict__ f1W,
                       const float* __restrict__ f2W, const float* __restrict__ qkvW,
                       u16* __restrict__ owt, u16* __restrict__ f1t,
                       u16* __restrict__ f2t, u16* __restrict__ qwt){
  int idx = blockIdx.x*256 + threadIdx.x;
  const int NT = 391*256;
  if (idx < NODES) counts[idx] = 0;
  if (idx < NG*64) pooled[idx] = 0.f;
  if (idx < 49152){
    int L = idx >> 13, r = idx & 8191, j = r >> 6, k = r & 63;   // w1t[L][j=out128][k=in64]
    w1t_g[idx] = f2bf(m1W[(L << 13) + k*128 + j]);
  }
  if (idx < 98304 && idx >= 49152){
    int t = idx - 49152;
    int L = t >> 13, r = t & 8191, j = r >> 7, k = r & 127;      // w2t[L][j=out64][k=in128]
    w2t_g[t] = f2bf(m2W[(L << 13) + k*64 + j]);
  }
  for (int i = idx; i < 98304; i += NT){        // 6 layers x 16384
    owt[i] = f2bf(outW[i]);
    f1t[i] = f2bf(f1W[i]);
    f2t[i] = f2bf(f2W[i]);
  }
  for (int i = idx; i < 294912; i += NT)        // 6 layers x 49152
    qwt[i] = f2bf(qkvW[i]);
}

// ---------------- CSR build ----------------
__global__ void k_hist(const int* __restrict__ dst, int* __restrict__ counts){
  int e = blockIdx.x*256 + threadIdx.x;
  if (e < EDGES) atomicAdd(&counts[dst[e]], 1);
}

__global__ void k_scan1(const int* __restrict__ counts, int* __restrict__ rowptr, int* __restrict__ bsums){
  __shared__ int sd[256];
  int tid = threadIdx.x;
  int base = blockIdx.x*2048 + tid*8;
  int v[8]; int s = 0;
  #pragma unroll
  for (int i = 0; i < 8; i++){
    int idx = base + i;
    int c = (idx < NODES) ? counts[idx] : 0;
    v[i] = s; s += c;
  }
  sd[tid] = s;
  __syncthreads();
  for (int off = 1; off < 256; off <<= 1){
    int t = 0;
    if (tid >= off) t = sd[tid - off];
    __syncthreads();
    if (tid >= off) sd[tid] += t;
    __syncthreads();
  }
  int excl = (tid > 0) ? sd[tid-1] : 0;
  #pragma unroll
  for (int i = 0; i < 8; i++){
    int idx = base + i;
    if (idx < NODES) rowptr[idx] = v[i] + excl;
  }
  if (tid == 255) bsums[blockIdx.x] = sd[255];
}

__global__ void k_scan2(const int* __restrict__ bsums, int* __restrict__ boffs, int nb){
  int tid = threadIdx.x;
  int acc = 0;
  for (int j = 0; j < nb; j++){
    int b = bsums[j];
    if (j < tid) acc += b;
  }
  if (tid < nb) boffs[tid] = acc;
}

__global__ void k_scan3(int* __restrict__ rowptr, int* __restrict__ cursor, const int* __restrict__ boffs){
  int i = blockIdx.x*256 + threadIdx.x;
  if (i < NODES){
    int r = rowptr[i] + boffs[i >> 11];
    rowptr[i] = r; cursor[i] = r;
  }
  if (i == 0) rowptr[NODES] = EDGES;
}

__global__ void k_scatter(const int* __restrict__ src, const int* __restrict__ dst,
                          int* __restrict__ cursor, int* __restrict__ esrc){
  int e = blockIdx.x*256 + threadIdx.x;
  if (e < EDGES){
    int d = dst[e];
    int p = atomicAdd(&cursor[d], 1);
    esrc[p] = src[e];
  }
}

// ---------------- encoder: h = x@W+b (bf16) ; z = relu(LN(h)) (bf16) ----------------
__global__ __launch_bounds__(256) void k_enc(const float* __restrict__ x,
    const float* __restrict__ encW, const float* __restrict__ encb,
    const float* __restrict__ lg, const float* __restrict__ lb,
    u16* __restrict__ hbf, u16* __restrict__ z){
  __shared__ float we[320], wb[64], sg[64], sb[64];
  int tid = threadIdx.x;
  for (int i = tid; i < 320; i += 256) we[i] = encW[i];
  if (tid < 64){ wb[tid] = encb[tid]; sg[tid] = lg[tid]; sb[tid] = lb[tid]; }
  __syncthreads();
  int n = blockIdx.x*256 + tid;
  if (n >= NODES) return;
  float xv[5];
  #pragma unroll
  for (int k = 0; k < 5; k++) xv[k] = x[n*5 + k];
  float a[64];
  #pragma unroll
  for (int c = 0; c < 64; c++){
    float t = wb[c];
    #pragma unroll
    for (int k = 0; k < 5; k++) t += xv[k]*we[k*64 + c];
    a[c] = t;
  }
  float mean = 0.f;
  #pragma unroll
  for (int c = 0; c < 64; c++) mean += a[c];
  mean *= (1.f/64.f);
  float var = 0.f;
  #pragma unroll
  for (int c = 0; c < 64; c++){ float d = a[c]-mean; var += d*d; }
  var *= (1.f/64.f);
  float rstd = rsqrtf(var + 1e-5f);
  size_t rb = (size_t)n*64;
  #pragma unroll
  for (int c = 0; c < 64; c += 4){
    uint2 hv;
    hv.x = pk2(a[c], a[c+1]); hv.y = pk2(a[c+2], a[c+3]);
    *(uint2*)&hbf[rb + c] = hv;
    uint2 zv;
    zv.x = pk2(fmaxf((a[c  ]-mean)*rstd*sg[c  ]+sb[c  ], 0.f),
               fmaxf((a[c+1]-mean)*rstd*sg[c+1]+sb[c+1], 0.f));
    zv.y = pk2(fmaxf((a[c+2]-mean)*rstd*sg[c+2]+sb[c+2], 0.f),
               fmaxf((a[c+3]-mean)*rstd*sg[c+3]+sb[c+3], 0.f));
    *(uint2*)&z[rb + c] = zv;
  }
}

// ---------------- GENConv softmax aggregation: 8 nodes/wave, uint4 = 8 channels/lane ----------------
__global__ __launch_bounds__(256) void k_agg(const uint4* __restrict__ zq, uint4* __restrict__ uo,
    const int* __restrict__ rowptr, const int* __restrict__ esrc,
    const float* __restrict__ tparam, int li){
  int lane = threadIdx.x & 63;
  int sub = lane >> 3;           // node-of-8 within wave
  int cl  = lane & 7;            // uint4 index within 128B row (8 bf16 channels)
  int n = blockIdx.x*32 + (threadIdx.x >> 6)*8 + sub;
  if (n >= NODES) return;
  float tp = tparam[li];
  int beg = rowptr[n], end = rowptr[n+1];
  uint4 zp = zq[(size_t)n*8 + cl];
  float zn[8];
  zn[0] = bfL(zp.x); zn[1] = bfH(zp.x); zn[2] = bfL(zp.y); zn[3] = bfH(zp.y);
  zn[4] = bfL(zp.z); zn[5] = bfH(zp.z); zn[6] = bfL(zp.w); zn[7] = bfH(zp.w);
  float den[8], num[8];
  #pragma unroll
  for (int c = 0; c < 8; c++){ den[c] = 0.f; num[c] = 0.f; }
  int e = beg;
  for (; e + 7 < end; e += 8){                  // 8-deep gather chain, 8 ch/lane
    int si[8];
    #pragma unroll
    for (int r = 0; r < 8; r++) si[r] = esrc[e + r];
    uint4 vv[8];
    #pragma unroll
    for (int r = 0; r < 8; r++) vv[r] = zq[(size_t)si[r]*8 + cl];
    #pragma unroll
    for (int r = 0; r < 8; r++){
      float m[8];
      m[0] = bfL(vv[r].x) + 1e-7f; m[1] = bfH(vv[r].x) + 1e-7f;
      m[2] = bfL(vv[r].y) + 1e-7f; m[3] = bfH(vv[r].y) + 1e-7f;
      m[4] = bfL(vv[r].z) + 1e-7f; m[5] = bfH(vv[r].z) + 1e-7f;
      m[6] = bfL(vv[r].w) + 1e-7f; m[7] = bfH(vv[r].w) + 1e-7f;
      #pragma unroll
      for (int c = 0; c < 8; c++){
        float ex = __expf(m[c]*tp);
        den[c] += ex; num[c] += m[c]*ex;
      }
    }
  }
  for (; e + 3 < end; e += 4){
    int si[4];
    #pragma unroll
    for (int r = 0; r < 4; r++) si[r] = esrc[e + r];
    uint4 vv[4];
    #pragma unroll
    for (int r = 0; r < 4; r++) vv[r] = zq[(size_t)si[r]*8 + cl];
    #pragma unroll
    for (int r = 0; r < 4; r++){
      float m[8];
      m[0] = bfL(vv[r].x) + 1e-7f; m[1] = bfH(vv[r].x) + 1e-7f;
      m[2] = bfL(vv[r].y) + 1e-7f; m[3] = bfH(vv[r].y) + 1e-7f;
      m[4] = bfL(vv[r].z) + 1e-7f; m[5] = bfH(vv[r].z) + 1e-7f;
      m[6] = bfL(vv[r].w) + 1e-7f; m[7] = bfH(vv[r].w) + 1e-7f;
      #pragma unroll
      for (int c = 0; c < 8; c++){
        float ex = __expf(m[c]*tp);
        den[c] += ex; num[c] += m[c]*ex;
      }
    }
  }
  for (; e < end; ++e){
    uint4 v = zq[(size_t)esrc[e]*8 + cl];
    float m[8];
    m[0] = bfL(v.x) + 1e-7f; m[1] = bfH(v.x) + 1e-7f;
    m[2] = bfL(v.y) + 1e-7f; m[3] = bfH(v.y) + 1e-7f;
    m[4] = bfL(v.z) + 1e-7f; m[5] = bfH(v.z) + 1e-7f;
    m[6] = bfL(v.w) + 1e-7f; m[7] = bfH(v.w) + 1e-7f;
    #pragma unroll
    for (int c = 0; c < 8; c++){
      float ex = __expf(m[c]*tp);
      den[c] += ex; num[c] += m[c]*ex;
    }
  }
  float uv[8];
  #pragma unroll
  for (int c = 0; c < 8; c++) uv[c] = zn[c] + num[c] / fmaxf(den[c], 1e-16f);
  uint4 o;
  o.x = pk2(uv[0], uv[1]); o.y = pk2(uv[2], uv[3]);
  o.z = pk2(uv[4], uv[5]); o.w = pk2(uv[6], uv[7]);
  uo[(size_t)n*8 + cl] = o;
}

// ---------------- MFMA node MLP: 128 nodes/block, reg-only act exchange, h prefetched ----------------
__global__ __launch_bounds__(256) void k_mlpm(
    const u16* __restrict__ u, u16* __restrict__ hbf, u16* __restrict__ znext,
    float* __restrict__ pooled, const int* __restrict__ batch,
    const u16* __restrict__ w1t_g, const u16* __restrict__ w2t_g,
    const float* __restrict__ B1, const float* __restrict__ G1, const float* __restrict__ Q1,
    const float* __restrict__ B2, const float* __restrict__ GN, const float* __restrict__ BN,
    int last){
  __shared__ u16 w1t[128*88];
  __shared__ u16 w2t[64*152];
  __shared__ float cb1[128], cg1[128], cq1[128];
  __shared__ float cb2[64], cgn[64], cbn[64];
  int tid = threadIdx.x;
  const uint4* w1g = (const uint4*)w1t_g;
  const uint4* w2g = (const uint4*)w2t_g;
  for (int i = tid; i < 1024; i += 256){
    { int j = i >> 3, c = i & 7;  *(uint4*)&w1t[j*88  + c*8] = w1g[i]; }
    { int j = i >> 4, c = i & 15; *(uint4*)&w2t[j*152 + c*8] = w2g[i]; }
  }
  if (tid < 128){ cb1[tid] = B1[tid]; cg1[tid] = G1[tid]; cq1[tid] = Q1[tid]; }
  if (tid < 64){
    cb2[tid] = B2[tid];
    cgn[tid] = last ? 0.f : GN[tid];
    cbn[tid] = last ? 0.f : BN[tid];
  }
  __syncthreads();

  int w = tid >> 6, l = tid & 63, l15 = l & 15, g = l >> 4;
  int nd = w*16 + l15;
  int base0 = blockIdx.x*128;
  int hi = g >> 1;
  int s0l = ((g & 1) << 5) + l15;
  int s1l = s0l + 16;
  f32x4 zero4 = {0.f, 0.f, 0.f, 0.f};
  bf16x8 bz8 = {0,0,0,0,0,0,0,0};

  // hoist u loads AND h residual loads for both iterations (overlap global latency with MFMA)
  bf16x8 buA[2], buB[2];
  uint2 hvp[2][4];
  #pragma unroll
  for (int it = 0; it < 2; it++){
    int node = base0 + it*64 + nd;
    bool ok = node < NODES;
    buA[it] = ok ? *(const bf16x8*)&u[(size_t)node*64 +      g*8] : bz8;
    buB[it] = ok ? *(const bf16x8*)&u[(size_t)node*64 + 32 + g*8] : bz8;
    #pragma unroll
    for (int mt = 0; mt < 4; mt++){
      uint2 hv = make_uint2(0u, 0u);
      if (ok) hv = *(const uint2*)&hbf[(size_t)node*64 + mt*16 + g*4];
      hvp[it][mt] = hv;
    }
  }

  #pragma unroll
  for (int it = 0; it < 2; it++){
    int node = base0 + it*64 + nd;
    bool ok = node < NODES;
    f32x4 c1[8];
    #pragma unroll
    for (int mt = 0; mt < 8; mt++) c1[mt] = zero4;
    #pragma unroll
    for (int mt = 0; mt < 8; mt++){
      bf16x8 aw0 = *(const bf16x8*)&w1t[(mt*16 + l15)*88 +      g*8];
      c1[mt] = __builtin_amdgcn_mfma_f32_16x16x32_bf16(aw0, buA[it], c1[mt], 0, 0, 0);
      bf16x8 aw1 = *(const bf16x8*)&w1t[(mt*16 + l15)*88 + 32 + g*8];
      c1[mt] = __builtin_amdgcn_mfma_f32_16x16x32_bf16(aw1, buB[it], c1[mt], 0, 0, 0);
    }
    float sum = 0.f, sq = 0.f;
    #pragma unroll
    for (int mt = 0; mt < 8; mt++){
      #pragma unroll
      for (int r = 0; r < 4; r++){
        float v = c1[mt][r] + cb1[mt*16 + g*4 + r];
        c1[mt][r] = v;
        sum += v; sq += v*v;
      }
    }
    sum += __shfl_xor(sum, 16); sum += __shfl_xor(sum, 32);
    sq  += __shfl_xor(sq, 16);  sq  += __shfl_xor(sq, 32);
    float mean = sum*(1.f/128.f);
    float var  = sq*(1.f/128.f) - mean*mean;
    float rstd = rsqrtf(fmaxf(var, 0.f) + 1e-5f);
    u32 pk0[8], pk1[8];
    #pragma unroll
    for (int mt = 0; mt < 8; mt++){
      int ch = mt*16 + g*4;
      float a0 = fmaxf((c1[mt][0]-mean)*rstd*cg1[ch  ] + cq1[ch  ], 0.f);
      float a1 = fmaxf((c1[mt][1]-mean)*rstd*cg1[ch+1] + cq1[ch+1], 0.f);
      float a2 = fmaxf((c1[mt][2]-mean)*rstd*cg1[ch+2] + cq1[ch+2], 0.f);
      float a3 = fmaxf((c1[mt][3]-mean)*rstd*cg1[ch+3] + cq1[ch+3], 0.f);
      pk0[mt] = pk2(a0, a1);
      pk1[mt] = pk2(a2, a3);
    }
    f32x4 c2[4];
    #pragma unroll
    for (int mt = 0; mt < 4; mt++) c2[mt] = zero4;
    #pragma unroll
    for (int ks = 0; ks < 4; ks++){
      u32 x0 = pk0[2*ks], x1 = pk0[2*ks+1];
      u32 y0 = pk1[2*ks], y1 = pk1[2*ks+1];
      u32 a0 = (u32)__shfl((int)x0, s0l), a1 = (u32)__shfl((int)x1, s0l);
      u32 b0 = (u32)__shfl((int)y0, s0l), b1 = (u32)__shfl((int)y1, s0l);
      u32 c0 = (u32)__shfl((int)x0, s1l), c1v = (u32)__shfl((int)x1, s1l);
      u32 d0 = (u32)__shfl((int)y0, s1l), d1 = (u32)__shfl((int)y1, s1l);
      union { u32 q[4]; bf16x8 v; } bb;
      bb.q[0] = hi ? a1 : a0;
      bb.q[1] = hi ? b1 : b0;
      bb.q[2] = hi ? c1v : c0;
      bb.q[3] = hi ? d1 : d0;
      #pragma unroll
      for (int mt = 0; mt < 4; mt++){
        bf16x8 aw = *(const bf16x8*)&w2t[(mt*16 + l15)*152 + ks*32 + g*8];
        c2[mt] = __builtin_amdgcn_mfma_f32_16x16x32_bf16(aw, bb.v, c2[mt], 0, 0, 0);
      }
    }
    if (ok){
      float out[16];
      size_t hb = (size_t)node*64;
      #pragma unroll
      for (int mt = 0; mt < 4; mt++){
        int ch = mt*16 + g*4;
        uint2 hv = hvp[it][mt];
        out[mt*4  ] = c2[mt][0] + cb2[ch  ] + bfL(hv.x);
        out[mt*4+1] = c2[mt][1] + cb2[ch+1] + bfH(hv.x);
        out[mt*4+2] = c2[mt][2] + cb2[ch+2] + bfL(hv.y);
        out[mt*4+3] = c2[mt][3] + cb2[ch+3] + bfH(hv.y);
      }
      if (!last){
        #pragma unroll
        for (int mt = 0; mt < 4; mt++){
          int ch = mt*16 + g*4;
          uint2 hv;
          hv.x = pk2(out[mt*4  ], out[mt*4+1]);
          hv.y = pk2(out[mt*4+2], out[mt*4+3]);
          *(uint2*)&hbf[hb + ch] = hv;
        }
        float s2 = 0.f, q2 = 0.f;
        #pragma unroll
        for (int c = 0; c < 16; c++){ s2 += out[c]; q2 += out[c]*out[c]; }
        s2 += __shfl_xor(s2, 16); s2 += __shfl_xor(s2, 32);
        q2 += __shfl_xor(q2, 16); q2 += __shfl_xor(q2, 32);
        float m2 = s2*(1.f/64.f);
        float v2 = q2*(1.f/64.f) - m2*m2;
        float rs2 = rsqrtf(fmaxf(v2, 0.f) + 1e-5f);
        #pragma unroll
        for (int mt = 0; mt < 4; mt++){
          int ch = mt*16 + g*4;
          uint2 pk;
          pk.x = pk2(fmaxf((out[mt*4  ]-m2)*rs2*cgn[ch  ] + cbn[ch  ], 0.f),
                     fmaxf((out[mt*4+1]-m2)*rs2*cgn[ch+1] + cbn[ch+1], 0.f));
          pk.y = pk2(fmaxf((out[mt*4+2]-m2)*rs2*cgn[ch+2] + cbn[ch+2], 0.f),
                     fmaxf((out[mt*4+3]-m2)*rs2*cgn[ch+3] + cbn[ch+3], 0.f));
          *(uint2*)&znext[hb + ch] = pk;
        }
      } else {
        int gb = batch[node];
        #pragma unroll
        for (int c = 0; c < 16; c++){
          int ch = (c >> 2)*16 + g*4 + (c & 3);
          atomicAdd(&pooled[gb*64 + ch], out[c]);
        }
      }
    }
  }
}

// ---------------- pooled + var MLP -> t ; qkv (bf16) for layer 0 ----------------
__global__ __launch_bounds__(128) void k_pool2(
    const float* __restrict__ pooled, const float* __restrict__ var_data,
    const float* __restrict__ v1W, const float* __restrict__ v1b,
    const float* __restrict__ v2W, const float* __restrict__ v2b,
    const float* __restrict__ v3W, const float* __restrict__ v3b,
    float* __restrict__ t, u16* __restrict__ qkvout,
    const float* __restrict__ qW, const float* __restrict__ qb){
  __shared__ float vin[19], l1[16], l2[32], tr[128];
  int c = threadIdx.x, s = blockIdx.x;
  if (c < 19) vin[c] = var_data[s*19 + c];
  __syncthreads();
  if (c < 16){
    float a = v1b[c];
    for (int k = 0; k < 19; k++) a += vin[k]*v1W[k*16 + c];
    l1[c] = fmaxf(a, 0.f);
  }
  __syncthreads();
  if (c < 32){
    float a = v2b[c];
    for (int k = 0; k < 16; k++) a += l1[k]*v2W[k*32 + c];
    l2[c] = fmaxf(a, 0.f);
  }
  __syncthreads();
  float tv;
  if (c < 64) tv = pooled[s*64 + c];
  else {
    float a = v3b[c-64];
    for (int k = 0; k < 32; k++) a += l2[k]*v3W[k*64 + (c-64)];
    tv = a;
  }
  tr[c] = tv; t[s*128 + c] = tv;
  __syncthreads();
  #pragma unroll 1
  for (int r = 0; r < 3; r++){
    int col = r*128 + c;
    float a = qb[col];
    #pragma unroll 4
    for (int k = 0; k < 128; k++) a += tr[k]*qW[k*384 + col];
    qkvout[s*384 + col] = f2bf(a);
  }
}

// ---------------- fused encoder layer (256 blocks; bf16 qkv + bf16 weights) ----------------
__global__ __launch_bounds__(256) void k_attrow(
    const u16* __restrict__ qkv, float* __restrict__ t, u16* __restrict__ qkvout,
    const u16* __restrict__ outWb, const float* __restrict__ outb,
    const float* __restrict__ l1g, const float* __restrict__ l1b,
    const u16* __restrict__ f1Wb, const float* __restrict__ f1b,
    const u16* __restrict__ f2Wb, const float* __restrict__ f2b,
    const float* __restrict__ l2g, const float* __restrict__ l2b,
    const u16* __restrict__ qWb, const float* __restrict__ qb,
    const float* __restrict__ hW, const float* __restrict__ hb2,
    float* __restrict__ dout, int last){
  __shared__ float kv[8448];
  __shared__ float sc[8*260];
  __shared__ float qrow[128], orow[128], strow[128], s1row[128], sfrow[128], t2row[128];
  __shared__ float red[4];
  int tid = threadIdx.x, s = blockIdx.x;
  const u32* qkv32 = (const u32*)qkv;
  if (tid < 128){ qrow[tid] = bf2f(qkv[(size_t)s*384 + tid]); strow[tid] = t[(size_t)s*128 + tid]; }
  for (int tile = 0; tile < 4; tile++){
    __syncthreads();
    for (int i = tid; i < 4096; i += 256){
      int r = i >> 6, c2 = i & 63;
      u32 v = qkv32[(size_t)(tile*64 + r)*192 + 64 + c2];
      kv[r*132 + c2*2    ] = bfL(v);
      kv[r*132 + c2*2 + 1] = bfH(v);
    }
    __syncthreads();
    int j = tid >> 2, sub = tid & 3;
    float d0 = 0.f, d1 = 0.f;
    #pragma unroll
    for (int d = 0; d < 16; d++){
      d0 += qrow[sub*16 + d]     * kv[j*132 + sub*16 + d];
      d1 += qrow[(sub+4)*16 + d] * kv[j*132 + (sub+4)*16 + d];
    }
    sc[sub*260     + tile*64 + j] = d0*0.25f;
    sc[(sub+4)*260 + tile*64 + j] = d1*0.25f;
  }
  __syncthreads();
  {
    int wid = tid >> 6, lane = tid & 63;
    #pragma unroll
    for (int hh = 0; hh < 2; hh++){
      int hh2 = wid*2 + hh;
      float a0 = sc[hh2*260 + lane], a1 = sc[hh2*260 + 64 + lane];
      float a2 = sc[hh2*260 + 128 + lane], a3 = sc[hh2*260 + 192 + lane];
      float m = wmax64(fmaxf(fmaxf(a0,a1), fmaxf(a2,a3)));
      float e0 = __expf(a0-m), e1 = __expf(a1-m), e2 = __expf(a2-m), e3 = __expf(a3-m);
      float sum = wsum64((e0+e1)+(e2+e3));
      float inv = 1.f/sum;
      sc[hh2*260 + lane] = e0*inv; sc[hh2*260 + 64 + lane] = e1*inv;
      sc[hh2*260 + 128 + lane] = e2*inv; sc[hh2*260 + 192 + lane] = e3*inv;
    }
  }
  float o = 0.f;
  int hme = (tid & 127) >> 4;
  for (int tile = 0; tile < 4; tile++){
    __syncthreads();
    for (int i = tid; i < 4096; i += 256){
      int r = i >> 6, c2 = i & 63;
      u32 v = qkv32[(size_t)(tile*64 + r)*192 + 128 + c2];
      kv[r*132 + c2*2    ] = bfL(v);
      kv[r*132 + c2*2 + 1] = bfH(v);
    }
    __syncthreads();
    if (tid < 128){
      #pragma unroll 4
      for (int j = 0; j < 64; j++)
        o += sc[hme*260 + tile*64 + j] * kv[j*132 + tid];
    }
  }
  if (tid < 128) orow[tid] = o;
  float acc = (tid < 128) ? outb[tid] : 0.f;
  {
    const u32* w32 = (const u32*)outWb;
    for (int kt = 0; kt < 4; kt++){
      __syncthreads();
      for (int i = tid; i < 2048; i += 256){
        u32 v = w32[kt*2048 + i];
        kv[i*2] = bfL(v); kv[i*2 + 1] = bfH(v);
      }
      __syncthreads();
      if (tid < 128){
        #pragma unroll 8
        for (int kk = 0; kk < 32; kk++) acc += orow[kt*32 + kk]*kv[kk*128 + tid];
      }
    }
  }
  if (tid < 128) acc += strow[tid];
  float mean = bsum256((tid < 128) ? acc : 0.f, red)*(1.f/128.f);
  float d0v = (tid < 128) ? (acc - mean) : 0.f;
  float var = bsum256(d0v*d0v, red)*(1.f/128.f);
  float t1 = 0.f;
  if (tid < 128){
    t1 = d0v*rsqrtf(var + 1e-5f)*l1g[tid] + l1b[tid];
    s1row[tid] = t1;
  }
  float f = (tid < 128) ? f1b[tid] : 0.f;
  {
    const u32* w32 = (const u32*)f1Wb;
    for (int kt = 0; kt < 4; kt++){
      __syncthreads();
      for (int i = tid; i < 2048; i += 256){
        u32 v = w32[kt*2048 + i];
        kv[i*2] = bfL(v); kv[i*2 + 1] = bfH(v);
      }
      __syncthreads();
      if (tid < 128){
        #pragma unroll 8
        for (int kk = 0; kk < 32; kk++) f += s1row[kt*32 + kk]*kv[kk*128 + tid];
      }
    }
  }
  if (tid < 128){
    f = 0.5f*f*(1.f + erff(f*0.70710678118654752f));
    sfrow[tid] = f;
  }
  float g = (tid < 128) ? f2b[tid] : 0.f;
  {
    const u32* w32 = (const u32*)f2Wb;
    for (int kt = 0; kt < 4; kt++){
      __syncthreads();
      for (int i = tid; i < 2048; i += 256){
        u32 v = w32[kt*2048 + i];
        kv[i*2] = bfL(v); kv[i*2 + 1] = bfH(v);
      }
      __syncthreads();
      if (tid < 128){
        #pragma unroll 8
        for (int kk = 0; kk < 32; kk++) g += sfrow[kt*32 + kk]*kv[kk*128 + tid];
      }
    }
  }
  if (tid < 128) g += t1;
  float mean2 = bsum256((tid < 128) ? g : 0.f, red)*(1.f/128.f);
  float d2v = (tid < 128) ? (g - mean2) : 0.f;
  float var2 = bsum256(d2v*d2v, red)*(1.f/128.f);
  if (tid < 128){
    float t2 = d2v*rsqrtf(var2 + 1e-5f)*l2g[tid] + l2b[tid];
    t[(size_t)s*128 + tid] = t2;
    t2row[tid] = t2;
  }
  __syncthreads();
  if (!last){
    float a0 = qb[tid];
    float a1 = (tid < 128) ? qb[256 + tid] : 0.f;
    const u32* w32 = (const u32*)qWb;
    for (int kt = 0; kt < 8; kt++){
      __syncthreads();
      for (int i = tid; i < 3072; i += 256){
        u32 v = w32[kt*3072 + i];
        kv[i*2] = bfL(v); kv[i*2 + 1] = bfH(v);
      }
      __syncthreads();
      #pragma unroll 4
      for (int kk = 0; kk < 16; kk++){
        float tv = t2row[kt*16 + kk];
        a0 += tv*kv[kk*384 + tid];
        if (tid < 128) a1 += tv*kv[kk*384 + 256 + tid];
      }
    }
    qkvout[(size_t)s*384 + tid] = f2bf(a0);
    if (tid < 128) qkvout[(size_t)s*384 + 256 + tid] = f2bf(a1);
  } else {
    if (tid < 2){
      float a = hb2[tid];
      for (int k = 0; k < 128; k++) a += t2row[k]*hW[k*2 + tid];
      dout[s*2 + tid] = a;
    }
  }
}

// ---------------- host ----------------
extern "C" void kernel_launch(void* const* d_in, const int* in_sizes, int n_in,
                              void* d_out, int out_size, void* d_ws, size_t ws_size,
                              hipStream_t stream){
  const float* x       = (const float*)d_in[0];
  const int*   ei      = (const int*)  d_in[1];
  const int*   batch   = (const int*)  d_in[2];
  const float* var_d   = (const float*)d_in[3];
  const float* encW    = (const float*)d_in[4];
  const float* encb    = (const float*)d_in[5];
  const float* ln_g    = (const float*)d_in[6];
  const float* ln_b    = (const float*)d_in[7];
  const float* tparam  = (const float*)d_in[8];
  const float* m1W     = (const float*)d_in[9];
  const float* m1b     = (const float*)d_in[10];
  const float* mng     = (const float*)d_in[11];
  const float* mnb     = (const float*)d_in[12];
  const float* m2W     = (const float*)d_in[13];
  const float* m2b     = (const float*)d_in[14];
  const float* v1W     = (const float*)d_in[15];
  const float* v1b     = (const float*)d_in[16];
  const float* v2W     = (const float*)d_in[17];
  const float* v2b     = (const float*)d_in[18];
  const float* v3W     = (const float*)d_in[19];
  const float* v3b     = (const float*)d_in[20];
  const float* qkvW    = (const float*)d_in[21];
  const float* qkvB    = (const float*)d_in[22];
  const float* outW    = (const float*)d_in[23];
  const float* outb    = (const float*)d_in[24];
  const float* l1g     = (const float*)d_in[25];
  const float* l1b     = (const float*)d_in[26];
  const float* f1W     = (const float*)d_in[27];
  const float* f1b     = (const float*)d_in[28];
  const float* f2W     = (const float*)d_in[29];
  const float* f2b     = (const float*)d_in[30];
  const float* l2g     = (const float*)d_in[31];
  const float* l2b     = (const float*)d_in[32];
  const float* headW   = (const float*)d_in[33];
  const float* headB   = (const float*)d_in[34];
  float* dout = (float*)d_out;

  char* wsb = (char*)d_ws;
  size_t off = 0;
  auto nxt = [&](size_t bytes)->void*{
    void* p = wsb + off;
    off += (bytes + 255) & ~(size_t)255;
    return p;
  };
  u16*   h      = (u16*)  nxt((size_t)NODES*64*2);
  u16*   z      = (u16*)  nxt((size_t)NODES*64*2);
  u16*   u      = (u16*)  nxt((size_t)NODES*64*2);
  int*   rowptr = (int*)  nxt((size_t)(NODES+1)*4);
  int*   cursor = (int*)  nxt((size_t)NODES*4);
  int*   counts = (int*)  nxt((size_t)NODES*4);
  int*   bsums  = (int*)  nxt(64*4);
  int*   boffs  = (int*)  nxt(64*4);
  int*   esrc   = (int*)  nxt((size_t)EDGES*4);
  float* pooled = (float*)nxt((size_t)NG*64*4);
  float* tbuf   = (float*)nxt((size_t)NG*128*4);
  u16*   qkv0   = (u16*)  nxt((size_t)NG*384*2);
  u16*   qkv1   = (u16*)  nxt((size_t)NG*384*2);
  u16*   w1tg   = (u16*)  nxt((size_t)49152*2);
  u16*   w2tg   = (u16*)  nxt((size_t)49152*2);
  u16*   owt    = (u16*)  nxt((size_t)98304*2);
  u16*   f1t    = (u16*)  nxt((size_t)98304*2);
  u16*   f2t    = (u16*)  nxt((size_t)98304*2);
  u16*   qwt    = (u16*)  nxt((size_t)294912*2);
  u16*   qkvb[2] = { qkv0, qkv1 };

  const int* srcp = ei;
  const int* dstp = ei + EDGES;

  k_init   <<<391, 256, 0, stream>>>(counts, pooled, m1W, m2W, w1tg, w2tg,
                                     outW, f1W, f2W, qkvW, owt, f1t, f2t, qwt);
  k_hist   <<<4688, 256, 0, stream>>>(dstp, counts);
  k_scan1  <<<49, 256, 0, stream>>>(counts, rowptr, bsums);
  k_scan2  <<<1, 64, 0, stream>>>(bsums, boffs, 49);
  k_scan3  <<<391, 256, 0, stream>>>(rowptr, cursor, boffs);
  k_scatter<<<4688, 256, 0, stream>>>(srcp, dstp, cursor, esrc);
  k_enc    <<<391, 256, 0, stream>>>(x, encW, encb, ln_g, ln_b, h, z);

  for (int i = 0; i < 6; i++){
    int last = (i == 5);
    k_agg <<<3125, 256, 0, stream>>>((const uint4*)z, (uint4*)u, rowptr, esrc, tparam, i);
    k_mlpm<<<782, 256, 0, stream>>>(u, h, z, pooled, batch,
        w1tg + i*8192, w2tg + i*8192,
        m1b + i*128, mng + i*128, mnb + i*128,
        m2b + i*64,
        ln_g + (last ? 0 : (i+1)*64), ln_b + (last ? 0 : (i+1)*64), last);
  }

  k_pool2<<<NG, 128, 0, stream>>>(pooled, var_d, v1W, v1b, v2W, v2b, v3W, v3b,
                                  tbuf, qkv0, qkvW, qkvB);

  for (int i = 0; i < 6; i++){
    int last = (i == 5);
    k_attrow<<<NG, 256, 0, stream>>>(qkvb[i & 1], tbuf, qkvb[(i + 1) & 1],
        owt + i*16384, outb + i*128, l1g + i*128, l1b + i*128,
        f1t + i*16384, f1b + i*128, f2t + i*16384, f2b + i*128,
        l2g + i*128, l2b + i*128,
        qwt + (size_t)(last ? 0 : (i+1))*49152, qkvB + (last ? 0 : (i+1))*384,
        headW, headB, dout, last);
  }
}

// Round 15
// 1415.135 us; speedup vs baseline: 1.0159x; 1.0159x over previous
//
#include <hip/hip_runtime.h>
#include <hip/hip_bf16.h>
#include <math.h>

#define NODES 100000
#define EDGES 1200000
#define NG 256

typedef unsigned short u16;
typedef unsigned int   u32;
typedef __attribute__((ext_vector_type(8))) short bf16x8;
typedef __attribute__((ext_vector_type(4))) float f32x4;

__device__ __forceinline__ u16 f2bf(float f){
  u32 u = __float_as_uint(f);
  u32 r = (u + 0x7FFFu + ((u >> 16) & 1u)) >> 16;
  return (u16)r;
}
__device__ __forceinline__ float bf2f(u16 b){ return __uint_as_float(((u32)b) << 16); }
__device__ __forceinline__ float bfL(u32 v){ return __uint_as_float(v << 16); }
__device__ __forceinline__ float bfH(u32 v){ return __uint_as_float(v & 0xFFFF0000u); }
__device__ __forceinline__ u32 pk2(float a, float b){ return (u32)f2bf(a) | ((u32)f2bf(b) << 16); }

// ---------------- utility ----------------
__device__ __forceinline__ float wsum64(float v){
  v += __shfl_xor(v, 32); v += __shfl_xor(v, 16); v += __shfl_xor(v, 8);
  v += __shfl_xor(v, 4);  v += __shfl_xor(v, 2);  v += __shfl_xor(v, 1);
  return v;
}
__device__ __forceinline__ float wmax64(float v){
  v = fmaxf(v, __shfl_xor(v, 32)); v = fmaxf(v, __shfl_xor(v, 16));
  v = fmaxf(v, __shfl_xor(v, 8));  v = fmaxf(v, __shfl_xor(v, 4));
  v = fmaxf(v, __shfl_xor(v, 2));  v = fmaxf(v, __shfl_xor(v, 1));
  return v;
}
__device__ __forceinline__ float bsum256(float v, float* red){
  v = wsum64(v);
  if ((threadIdx.x & 63) == 0) red[threadIdx.x >> 6] = v;
  __syncthreads();
  float r = red[0] + red[1] + red[2] + red[3];
  __syncthreads();
  return r;
}

// ---------------- init: zero + ALL weight pre-transposes/conversions to bf16 ----------------
__global__ void k_init(int* counts, float* pooled,
                       const float* __restrict__ m1W, const float* __restrict__ m2W,
                       u16* __restrict__ w1t_g, u16* __restrict__ w2t_g,
                       const float* __restrict__ outW, const float* __restrict__ f1W,
                       const float* __restrict__ f2W, const float* __restrict__ qkvW,
                       u16* __restrict__ owt, u16* __restrict__ f1t,
                       u16* __restrict__ f2t, u16* __restrict__ qwt){
  int idx = blockIdx.x*256 + threadIdx.x;
  const int NT = 391*256;
  if (idx < NODES) counts[idx] = 0;
  if (idx < NG*64) pooled[idx] = 0.f;
  if (idx < 49152){
    int L = idx >> 13, r = idx & 8191, j = r >> 6, k = r & 63;   // w1t[L][j=out128][k=in64]
    w1t_g[idx] = f2bf(m1W[(L << 13) + k*128 + j]);
  }
  if (idx < 98304 && idx >= 49152){
    int t = idx - 49152;
    int L = t >> 13, r = t & 8191, j = r >> 7, k = r & 127;      // w2t[L][j=out64][k=in128]
    w2t_g[t] = f2bf(m2W[(L << 13) + k*64 + j]);
  }
  for (int i = idx; i < 98304; i += NT){        // 6 layers x 16384
    owt[i] = f2bf(outW[i]);
    f1t[i] = f2bf(f1W[i]);
    f2t[i] = f2bf(f2W[i]);
  }
  for (int i = idx; i < 294912; i += NT)        // 6 layers x 49152
    qwt[i] = f2bf(qkvW[i]);
}

// ---------------- CSR build ----------------
__global__ void k_hist(const int* __restrict__ dst, int* __restrict__ counts){
  int e = blockIdx.x*256 + threadIdx.x;
  if (e < EDGES) atomicAdd(&counts[dst[e]], 1);
}

__global__ void k_scan1(const int* __restrict__ counts, int* __restrict__ rowptr, int* __restrict__ bsums){
  __shared__ int sd[256];
  int tid = threadIdx.x;
  int base = blockIdx.x*2048 + tid*8;
  int v[8]; int s = 0;
  #pragma unroll
  for (int i = 0; i < 8; i++){
    int idx = base + i;
    int c = (idx < NODES) ? counts[idx] : 0;
    v[i] = s; s += c;
  }
  sd[tid] = s;
  __syncthreads();
  for (int off = 1; off < 256; off <<= 1){
    int t = 0;
    if (tid >= off) t = sd[tid - off];
    __syncthreads();
    if (tid >= off) sd[tid] += t;
    __syncthreads();
  }
  int excl = (tid > 0) ? sd[tid-1] : 0;
  #pragma unroll
  for (int i = 0; i < 8; i++){
    int idx = base + i;
    if (idx < NODES) rowptr[idx] = v[i] + excl;
  }
  if (tid == 255) bsums[blockIdx.x] = sd[255];
}

__global__ void k_scan2(const int* __restrict__ bsums, int* __restrict__ boffs, int nb){
  int tid = threadIdx.x;
  int acc = 0;
  for (int j = 0; j < nb; j++){
    int b = bsums[j];
    if (j < tid) acc += b;
  }
  if (tid < nb) boffs[tid] = acc;
}

__global__ void k_scan3(int* __restrict__ rowptr, int* __restrict__ cursor, const int* __restrict__ boffs){
  int i = blockIdx.x*256 + threadIdx.x;
  if (i < NODES){
    int r = rowptr[i] + boffs[i >> 11];
    rowptr[i] = r; cursor[i] = r;
  }
  if (i == 0) rowptr[NODES] = EDGES;
}

__global__ void k_scatter(const int* __restrict__ src, const int* __restrict__ dst,
                          int* __restrict__ cursor, int* __restrict__ esrc){
  int e = blockIdx.x*256 + threadIdx.x;
  if (e < EDGES){
    int d = dst[e];
    int p = atomicAdd(&cursor[d], 1);
    esrc[p] = src[e];
  }
}

// ---------------- encoder: h = x@W+b (bf16) ; z = relu(LN(h)) (bf16) ----------------
__global__ __launch_bounds__(256) void k_enc(const float* __restrict__ x,
    const float* __restrict__ encW, const float* __restrict__ encb,
    const float* __restrict__ lg, const float* __restrict__ lb,
    u16* __restrict__ hbf, u16* __restrict__ z){
  __shared__ float we[320], wb[64], sg[64], sb[64];
  int tid = threadIdx.x;
  for (int i = tid; i < 320; i += 256) we[i] = encW[i];
  if (tid < 64){ wb[tid] = encb[tid]; sg[tid] = lg[tid]; sb[tid] = lb[tid]; }
  __syncthreads();
  int n = blockIdx.x*256 + tid;
  if (n >= NODES) return;
  float xv[5];
  #pragma unroll
  for (int k = 0; k < 5; k++) xv[k] = x[n*5 + k];
  float a[64];
  #pragma unroll
  for (int c = 0; c < 64; c++){
    float t = wb[c];
    #pragma unroll
    for (int k = 0; k < 5; k++) t += xv[k]*we[k*64 + c];
    a[c] = t;
  }
  float mean = 0.f;
  #pragma unroll
  for (int c = 0; c < 64; c++) mean += a[c];
  mean *= (1.f/64.f);
  float var = 0.f;
  #pragma unroll
  for (int c = 0; c < 64; c++){ float d = a[c]-mean; var += d*d; }
  var *= (1.f/64.f);
  float rstd = rsqrtf(var + 1e-5f);
  size_t rb = (size_t)n*64;
  #pragma unroll
  for (int c = 0; c < 64; c += 4){
    uint2 hv;
    hv.x = pk2(a[c], a[c+1]); hv.y = pk2(a[c+2], a[c+3]);
    *(uint2*)&hbf[rb + c] = hv;
    uint2 zv;
    zv.x = pk2(fmaxf((a[c  ]-mean)*rstd*sg[c  ]+sb[c  ], 0.f),
               fmaxf((a[c+1]-mean)*rstd*sg[c+1]+sb[c+1], 0.f));
    zv.y = pk2(fmaxf((a[c+2]-mean)*rstd*sg[c+2]+sb[c+2], 0.f),
               fmaxf((a[c+3]-mean)*rstd*sg[c+3]+sb[c+3], 0.f));
    *(uint2*)&z[rb + c] = zv;
  }
}

// ---------------- GENConv softmax aggregation: 4 nodes/wave, uint2 = 4 channels/lane ----------------
__global__ __launch_bounds__(256) void k_agg(const u32* __restrict__ z32, u32* __restrict__ uo,
    const int* __restrict__ rowptr, const int* __restrict__ esrc,
    const float* __restrict__ tparam, int li){
  int lane = threadIdx.x & 63;
  int q  = lane >> 4;
  int cl = lane & 15;
  int n = blockIdx.x*16 + (threadIdx.x >> 6)*4 + q;
  if (n >= NODES) return;
  float tp = tparam[li];
  int beg = rowptr[n], end = rowptr[n+1];
  const uint2* zq = (const uint2*)z32;
  uint2 zp = zq[(size_t)n*16 + cl];
  float zn0 = bfL(zp.x), zn1 = bfH(zp.x), zn2 = bfL(zp.y), zn3 = bfH(zp.y);
  float den0=0.f,num0=0.f,den1=0.f,num1=0.f,den2=0.f,num2=0.f,den3=0.f,num3=0.f;
  int e = beg;
  for (; e + 7 < end; e += 8){
    int si[8];
    #pragma unroll
    for (int r = 0; r < 8; r++) si[r] = esrc[e + r];
    uint2 vv[8];
    #pragma unroll
    for (int r = 0; r < 8; r++) vv[r] = zq[(size_t)si[r]*16 + cl];
    #pragma unroll
    for (int r = 0; r < 8; r++){
      float m0 = bfL(vv[r].x) + 1e-7f, m1 = bfH(vv[r].x) + 1e-7f;
      float m2 = bfL(vv[r].y) + 1e-7f, m3 = bfH(vv[r].y) + 1e-7f;
      float e0 = __expf(m0*tp), e1 = __expf(m1*tp), e2 = __expf(m2*tp), e3 = __expf(m3*tp);
      den0 += e0; num0 += m0*e0;
      den1 += e1; num1 += m1*e1;
      den2 += e2; num2 += m2*e2;
      den3 += e3; num3 += m3*e3;
    }
  }
  for (; e + 3 < end; e += 4){
    int si[4];
    #pragma unroll
    for (int r = 0; r < 4; r++) si[r] = esrc[e + r];
    uint2 vv[4];
    #pragma unroll
    for (int r = 0; r < 4; r++) vv[r] = zq[(size_t)si[r]*16 + cl];
    #pragma unroll
    for (int r = 0; r < 4; r++){
      float m0 = bfL(vv[r].x) + 1e-7f, m1 = bfH(vv[r].x) + 1e-7f;
      float m2 = bfL(vv[r].y) + 1e-7f, m3 = bfH(vv[r].y) + 1e-7f;
      float e0 = __expf(m0*tp), e1 = __expf(m1*tp), e2 = __expf(m2*tp), e3 = __expf(m3*tp);
      den0 += e0; num0 += m0*e0;
      den1 += e1; num1 += m1*e1;
      den2 += e2; num2 += m2*e2;
      den3 += e3; num3 += m3*e3;
    }
  }
  for (; e < end; ++e){
    uint2 v = zq[(size_t)esrc[e]*16 + cl];
    float m0 = bfL(v.x) + 1e-7f, m1 = bfH(v.x) + 1e-7f;
    float m2 = bfL(v.y) + 1e-7f, m3 = bfH(v.y) + 1e-7f;
    float e0 = __expf(m0*tp), e1 = __expf(m1*tp), e2 = __expf(m2*tp), e3 = __expf(m3*tp);
    den0 += e0; num0 += m0*e0;
    den1 += e1; num1 += m1*e1;
    den2 += e2; num2 += m2*e2;
    den3 += e3; num3 += m3*e3;
  }
  uint2 o;
  o.x = pk2(zn0 + num0 / fmaxf(den0, 1e-16f), zn1 + num1 / fmaxf(den1, 1e-16f));
  o.y = pk2(zn2 + num2 / fmaxf(den2, 1e-16f), zn3 + num3 / fmaxf(den3, 1e-16f));
  ((uint2*)uo)[(size_t)n*16 + cl] = o;
}

// ---------------- MFMA node MLP: 128 nodes/block, register-only act exchange, h bf16 ----------------
__global__ __launch_bounds__(256) void k_mlpm(
    const u16* __restrict__ u, u16* __restrict__ hbf, u16* __restrict__ znext,
    float* __restrict__ pooled, const int* __restrict__ batch,
    const u16* __restrict__ w1t_g, const u16* __restrict__ w2t_g,
    const float* __restrict__ B1, const float* __restrict__ G1, const float* __restrict__ Q1,
    const float* __restrict__ B2, const float* __restrict__ GN, const float* __restrict__ BN,
    int last){
  __shared__ u16 w1t[128*88];
  __shared__ u16 w2t[64*152];
  __shared__ float cb1[128], cg1[128], cq1[128];
  __shared__ float cb2[64], cgn[64], cbn[64];
  int tid = threadIdx.x;
  const uint4* w1g = (const uint4*)w1t_g;
  const uint4* w2g = (const uint4*)w2t_g;
  for (int i = tid; i < 1024; i += 256){
    { int j = i >> 3, c = i & 7;  *(uint4*)&w1t[j*88  + c*8] = w1g[i]; }
    { int j = i >> 4, c = i & 15; *(uint4*)&w2t[j*152 + c*8] = w2g[i]; }
  }
  if (tid < 128){ cb1[tid] = B1[tid]; cg1[tid] = G1[tid]; cq1[tid] = Q1[tid]; }
  if (tid < 64){
    cb2[tid] = B2[tid];
    cgn[tid] = last ? 0.f : GN[tid];
    cbn[tid] = last ? 0.f : BN[tid];
  }
  __syncthreads();

  int w = tid >> 6, l = tid & 63, l15 = l & 15, g = l >> 4;
  int nd = w*16 + l15;
  int base0 = blockIdx.x*128;
  int hi = g >> 1;
  int s0l = ((g & 1) << 5) + l15;
  int s1l = s0l + 16;
  f32x4 zero4 = {0.f, 0.f, 0.f, 0.f};
  bf16x8 bz8 = {0,0,0,0,0,0,0,0};

  bf16x8 buA[2], buB[2];
  #pragma unroll
  for (int it = 0; it < 2; it++){
    int node = base0 + it*64 + nd;
    bool ok = node < NODES;
    buA[it] = ok ? *(const bf16x8*)&u[(size_t)node*64 +      g*8] : bz8;
    buB[it] = ok ? *(const bf16x8*)&u[(size_t)node*64 + 32 + g*8] : bz8;
  }

  #pragma unroll
  for (int it = 0; it < 2; it++){
    int node = base0 + it*64 + nd;
    bool ok = node < NODES;
    f32x4 c1[8];
    #pragma unroll
    for (int mt = 0; mt < 8; mt++) c1[mt] = zero4;
    #pragma unroll
    for (int mt = 0; mt < 8; mt++){
      bf16x8 aw0 = *(const bf16x8*)&w1t[(mt*16 + l15)*88 +      g*8];
      c1[mt] = __builtin_amdgcn_mfma_f32_16x16x32_bf16(aw0, buA[it], c1[mt], 0, 0, 0);
      bf16x8 aw1 = *(const bf16x8*)&w1t[(mt*16 + l15)*88 + 32 + g*8];
      c1[mt] = __builtin_amdgcn_mfma_f32_16x16x32_bf16(aw1, buB[it], c1[mt], 0, 0, 0);
    }
    float sum = 0.f, sq = 0.f;
    #pragma unroll
    for (int mt = 0; mt < 8; mt++){
      #pragma unroll
      for (int r = 0; r < 4; r++){
        float v = c1[mt][r] + cb1[mt*16 + g*4 + r];
        c1[mt][r] = v;
        sum += v; sq += v*v;
      }
    }
    sum += __shfl_xor(sum, 16); sum += __shfl_xor(sum, 32);
    sq  += __shfl_xor(sq, 16);  sq  += __shfl_xor(sq, 32);
    float mean = sum*(1.f/128.f);
    float var  = sq*(1.f/128.f) - mean*mean;
    float rstd = rsqrtf(fmaxf(var, 0.f) + 1e-5f);
    u32 pk0[8], pk1[8];
    #pragma unroll
    for (int mt = 0; mt < 8; mt++){
      int ch = mt*16 + g*4;
      float a0 = fmaxf((c1[mt][0]-mean)*rstd*cg1[ch  ] + cq1[ch  ], 0.f);
      float a1 = fmaxf((c1[mt][1]-mean)*rstd*cg1[ch+1] + cq1[ch+1], 0.f);
      float a2 = fmaxf((c1[mt][2]-mean)*rstd*cg1[ch+2] + cq1[ch+2], 0.f);
      float a3 = fmaxf((c1[mt][3]-mean)*rstd*cg1[ch+3] + cq1[ch+3], 0.f);
      pk0[mt] = pk2(a0, a1);
      pk1[mt] = pk2(a2, a3);
    }
    f32x4 c2[4];
    #pragma unroll
    for (int mt = 0; mt < 4; mt++) c2[mt] = zero4;
    #pragma unroll
    for (int ks = 0; ks < 4; ks++){
      u32 x0 = pk0[2*ks], x1 = pk0[2*ks+1];
      u32 y0 = pk1[2*ks], y1 = pk1[2*ks+1];
      u32 a0 = (u32)__shfl((int)x0, s0l), a1 = (u32)__shfl((int)x1, s0l);
      u32 b0 = (u32)__shfl((int)y0, s0l), b1 = (u32)__shfl((int)y1, s0l);
      u32 c0 = (u32)__shfl((int)x0, s1l), c1v = (u32)__shfl((int)x1, s1l);
      u32 d0 = (u32)__shfl((int)y0, s1l), d1 = (u32)__shfl((int)y1, s1l);
      union { u32 q[4]; bf16x8 v; } bb;
      bb.q[0] = hi ? a1 : a0;
      bb.q[1] = hi ? b1 : b0;
      bb.q[2] = hi ? c1v : c0;
      bb.q[3] = hi ? d1 : d0;
      #pragma unroll
      for (int mt = 0; mt < 4; mt++){
        bf16x8 aw = *(const bf16x8*)&w2t[(mt*16 + l15)*152 + ks*32 + g*8];
        c2[mt] = __builtin_amdgcn_mfma_f32_16x16x32_bf16(aw, bb.v, c2[mt], 0, 0, 0);
      }
    }
    if (ok){
      float out[16];
      size_t hb = (size_t)node*64;
      #pragma unroll
      for (int mt = 0; mt < 4; mt++){
        int ch = mt*16 + g*4;
        uint2 hv = *(const uint2*)&hbf[hb + ch];
        out[mt*4  ] = c2[mt][0] + cb2[ch  ] + bfL(hv.x);
        out[mt*4+1] = c2[mt][1] + cb2[ch+1] + bfH(hv.x);
        out[mt*4+2] = c2[mt][2] + cb2[ch+2] + bfL(hv.y);
        out[mt*4+3] = c2[mt][3] + cb2[ch+3] + bfH(hv.y);
      }
      if (!last){
        #pragma unroll
        for (int mt = 0; mt < 4; mt++){
          int ch = mt*16 + g*4;
          uint2 hv;
          hv.x = pk2(out[mt*4  ], out[mt*4+1]);
          hv.y = pk2(out[mt*4+2], out[mt*4+3]);
          *(uint2*)&hbf[hb + ch] = hv;
        }
        float s2 = 0.f, q2 = 0.f;
        #pragma unroll
        for (int c = 0; c < 16; c++){ s2 += out[c]; q2 += out[c]*out[c]; }
        s2 += __shfl_xor(s2, 16); s2 += __shfl_xor(s2, 32);
        q2 += __shfl_xor(q2, 16); q2 += __shfl_xor(q2, 32);
        float m2 = s2*(1.f/64.f);
        float v2 = q2*(1.f/64.f) - m2*m2;
        float rs2 = rsqrtf(fmaxf(v2, 0.f) + 1e-5f);
        #pragma unroll
        for (int mt = 0; mt < 4; mt++){
          int ch = mt*16 + g*4;
          uint2 pk;
          pk.x = pk2(fmaxf((out[mt*4  ]-m2)*rs2*cgn[ch  ] + cbn[ch  ], 0.f),
                     fmaxf((out[mt*4+1]-m2)*rs2*cgn[ch+1] + cbn[ch+1], 0.f));
          pk.y = pk2(fmaxf((out[mt*4+2]-m2)*rs2*cgn[ch+2] + cbn[ch+2], 0.f),
                     fmaxf((out[mt*4+3]-m2)*rs2*cgn[ch+3] + cbn[ch+3], 0.f));
          *(uint2*)&znext[hb + ch] = pk;
        }
      } else {
        int gb = batch[node];
        #pragma unroll
        for (int c = 0; c < 16; c++){
          int ch = (c >> 2)*16 + g*4 + (c & 3);
          atomicAdd(&pooled[gb*64 + ch], out[c]);
        }
      }
    }
  }
}

// ---------------- pooled + var MLP -> t ; qkv (bf16) for layer 0 ----------------
__global__ __launch_bounds__(128) void k_pool2(
    const float* __restrict__ pooled, const float* __restrict__ var_data,
    const float* __restrict__ v1W, const float* __restrict__ v1b,
    const float* __restrict__ v2W, const float* __restrict__ v2b,
    const float* __restrict__ v3W, const float* __restrict__ v3b,
    float* __restrict__ t, u16* __restrict__ qkvout,
    const float* __restrict__ qW, const float* __restrict__ qb){
  __shared__ float vin[19], l1[16], l2[32], tr[128];
  int c = threadIdx.x, s = blockIdx.x;
  if (c < 19) vin[c] = var_data[s*19 + c];
  __syncthreads();
  if (c < 16){
    float a = v1b[c];
    for (int k = 0; k < 19; k++) a += vin[k]*v1W[k*16 + c];
    l1[c] = fmaxf(a, 0.f);
  }
  __syncthreads();
  if (c < 32){
    float a = v2b[c];
    for (int k = 0; k < 16; k++) a += l1[k]*v2W[k*32 + c];
    l2[c] = fmaxf(a, 0.f);
  }
  __syncthreads();
  float tv;
  if (c < 64) tv = pooled[s*64 + c];
  else {
    float a = v3b[c-64];
    for (int k = 0; k < 32; k++) a += l2[k]*v3W[k*64 + (c-64)];
    tv = a;
  }
  tr[c] = tv; t[s*128 + c] = tv;
  __syncthreads();
  #pragma unroll 1
  for (int r = 0; r < 3; r++){
    int col = r*128 + c;
    float a = qb[col];
    #pragma unroll 4
    for (int k = 0; k < 128; k++) a += tr[k]*qW[k*384 + col];
    qkvout[s*384 + col] = f2bf(a);
  }
}

// ---------------- fused encoder layer (256 blocks; bf16 qkv + bf16 weights) ----------------
__global__ __launch_bounds__(256) void k_attrow(
    const u16* __restrict__ qkv, float* __restrict__ t, u16* __restrict__ qkvout,
    const u16* __restrict__ outWb, const float* __restrict__ outb,
    const float* __restrict__ l1g, const float* __restrict__ l1b,
    const u16* __restrict__ f1Wb, const float* __restrict__ f1b,
    const u16* __restrict__ f2Wb, const float* __restrict__ f2b,
    const float* __restrict__ l2g, const float* __restrict__ l2b,
    const u16* __restrict__ qWb, const float* __restrict__ qb,
    const float* __restrict__ hW, const float* __restrict__ hb2,
    float* __restrict__ dout, int last){
  __shared__ float kv[8448];
  __shared__ float sc[8*260];
  __shared__ float qrow[128], orow[128], strow[128], s1row[128], sfrow[128], t2row[128];
  __shared__ float red[4];
  int tid = threadIdx.x, s = blockIdx.x;
  const u32* qkv32 = (const u32*)qkv;
  if (tid < 128){ qrow[tid] = bf2f(qkv[(size_t)s*384 + tid]); strow[tid] = t[(size_t)s*128 + tid]; }
  for (int tile = 0; tile < 4; tile++){
    __syncthreads();
    for (int i = tid; i < 4096; i += 256){
      int r = i >> 6, c2 = i & 63;
      u32 v = qkv32[(size_t)(tile*64 + r)*192 + 64 + c2];
      kv[r*132 + c2*2    ] = bfL(v);
      kv[r*132 + c2*2 + 1] = bfH(v);
    }
    __syncthreads();
    int j = tid >> 2, sub = tid & 3;
    float d0 = 0.f, d1 = 0.f;
    #pragma unroll
    for (int d = 0; d < 16; d++){
      d0 += qrow[sub*16 + d]     * kv[j*132 + sub*16 + d];
      d1 += qrow[(sub+4)*16 + d] * kv[j*132 + (sub+4)*16 + d];
    }
    sc[sub*260     + tile*64 + j] = d0*0.25f;
    sc[(sub+4)*260 + tile*64 + j] = d1*0.25f;
  }
  __syncthreads();
  {
    int wid = tid >> 6, lane = tid & 63;
    #pragma unroll
    for (int hh = 0; hh < 2; hh++){
      int hh2 = wid*2 + hh;
      float a0 = sc[hh2*260 + lane], a1 = sc[hh2*260 + 64 + lane];
      float a2 = sc[hh2*260 + 128 + lane], a3 = sc[hh2*260 + 192 + lane];
      float m = wmax64(fmaxf(fmaxf(a0,a1), fmaxf(a2,a3)));
      float e0 = __expf(a0-m), e1 = __expf(a1-m), e2 = __expf(a2-m), e3 = __expf(a3-m);
      float sum = wsum64((e0+e1)+(e2+e3));
      float inv = 1.f/sum;
      sc[hh2*260 + lane] = e0*inv; sc[hh2*260 + 64 + lane] = e1*inv;
      sc[hh2*260 + 128 + lane] = e2*inv; sc[hh2*260 + 192 + lane] = e3*inv;
    }
  }
  float o = 0.f;
  int hme = (tid & 127) >> 4;
  for (int tile = 0; tile < 4; tile++){
    __syncthreads();
    for (int i = tid; i < 4096; i += 256){
      int r = i >> 6, c2 = i & 63;
      u32 v = qkv32[(size_t)(tile*64 + r)*192 + 128 + c2];
      kv[r*132 + c2*2    ] = bfL(v);
      kv[r*132 + c2*2 + 1] = bfH(v);
    }
    __syncthreads();
    if (tid < 128){
      #pragma unroll 4
      for (int j = 0; j < 64; j++)
        o += sc[hme*260 + tile*64 + j] * kv[j*132 + tid];
    }
  }
  if (tid < 128) orow[tid] = o;
  float acc = (tid < 128) ? outb[tid] : 0.f;
  {
    const u32* w32 = (const u32*)outWb;
    for (int kt = 0; kt < 4; kt++){
      __syncthreads();
      for (int i = tid; i < 2048; i += 256){
        u32 v = w32[kt*2048 + i];
        kv[i*2] = bfL(v); kv[i*2 + 1] = bfH(v);
      }
      __syncthreads();
      if (tid < 128){
        #pragma unroll 8
        for (int kk = 0; kk < 32; kk++) acc += orow[kt*32 + kk]*kv[kk*128 + tid];
      }
    }
  }
  if (tid < 128) acc += strow[tid];
  float mean = bsum256((tid < 128) ? acc : 0.f, red)*(1.f/128.f);
  float d0v = (tid < 128) ? (acc - mean) : 0.f;
  float var = bsum256(d0v*d0v, red)*(1.f/128.f);
  float t1 = 0.f;
  if (tid < 128){
    t1 = d0v*rsqrtf(var + 1e-5f)*l1g[tid] + l1b[tid];
    s1row[tid] = t1;
  }
  float f = (tid < 128) ? f1b[tid] : 0.f;
  {
    const u32* w32 = (const u32*)f1Wb;
    for (int kt = 0; kt < 4; kt++){
      __syncthreads();
      for (int i = tid; i < 2048; i += 256){
        u32 v = w32[kt*2048 + i];
        kv[i*2] = bfL(v); kv[i*2 + 1] = bfH(v);
      }
      __syncthreads();
      if (tid < 128){
        #pragma unroll 8
        for (int kk = 0; kk < 32; kk++) f += s1row[kt*32 + kk]*kv[kk*128 + tid];
      }
    }
  }
  if (tid < 128){
    f = 0.5f*f*(1.f + erff(f*0.70710678118654752f));
    sfrow[tid] = f;
  }
  float g = (tid < 128) ? f2b[tid] : 0.f;
  {
    const u32* w32 = (const u32*)f2Wb;
    for (int kt = 0; kt < 4; kt++){
      __syncthreads();
      for (int i = tid; i < 2048; i += 256){
        u32 v = w32[kt*2048 + i];
        kv[i*2] = bfL(v); kv[i*2 + 1] = bfH(v);
      }
      __syncthreads();
      if (tid < 128){
        #pragma unroll 8
        for (int kk = 0; kk < 32; kk++) g += sfrow[kt*32 + kk]*kv[kk*128 + tid];
      }
    }
  }
  if (tid < 128) g += t1;
  float mean2 = bsum256((tid < 128) ? g : 0.f, red)*(1.f/128.f);
  float d2v = (tid < 128) ? (g - mean2) : 0.f;
  float var2 = bsum256(d2v*d2v, red)*(1.f/128.f);
  if (tid < 128){
    float t2 = d2v*rsqrtf(var2 + 1e-5f)*l2g[tid] + l2b[tid];
    t[(size_t)s*128 + tid] = t2;
    t2row[tid] = t2;
  }
  __syncthreads();
  if (!last){
    float a0 = qb[tid];
    float a1 = (tid < 128) ? qb[256 + tid] : 0.f;
    const u32* w32 = (const u32*)qWb;
    for (int kt = 0; kt < 8; kt++){
      __syncthreads();
      for (int i = tid; i < 3072; i += 256){
        u32 v = w32[kt*3072 + i];
        kv[i*2] = bfL(v); kv[i*2 + 1] = bfH(v);
      }
      __syncthreads();
      #pragma unroll 4
      for (int kk = 0; kk < 16; kk++){
        float tv = t2row[kt*16 + kk];
        a0 += tv*kv[kk*384 + tid];
        if (tid < 128) a1 += tv*kv[kk*384 + 256 + tid];
      }
    }
    qkvout[(size_t)s*384 + tid] = f2bf(a0);
    if (tid < 128) qkvout[(size_t)s*384 + 256 + tid] = f2bf(a1);
  } else {
    if (tid < 2){
      float a = hb2[tid];
      for (int k = 0; k < 128; k++) a += t2row[k]*hW[k*2 + tid];
      dout[s*2 + tid] = a;
    }
  }
}

// ---------------- host ----------------
extern "C" void kernel_launch(void* const* d_in, const int* in_sizes, int n_in,
                              void* d_out, int out_size, void* d_ws, size_t ws_size,
                              hipStream_t stream){
  const float* x       = (const float*)d_in[0];
  const int*   ei      = (const int*)  d_in[1];
  const int*   batch   = (const int*)  d_in[2];
  const float* var_d   = (const float*)d_in[3];
  const float* encW    = (const float*)d_in[4];
  const float* encb    = (const float*)d_in[5];
  const float* ln_g    = (const float*)d_in[6];
  const float* ln_b    = (const float*)d_in[7];
  const float* tparam  = (const float*)d_in[8];
  const float* m1W     = (const float*)d_in[9];
  const float* m1b     = (const float*)d_in[10];
  const float* mng     = (const float*)d_in[11];
  const float* mnb     = (const float*)d_in[12];
  const float* m2W     = (const float*)d_in[13];
  const float* m2b     = (const float*)d_in[14];
  const float* v1W     = (const float*)d_in[15];
  const float* v1b     = (const float*)d_in[16];
  const float* v2W     = (const float*)d_in[17];
  const float* v2b     = (const float*)d_in[18];
  const float* v3W     = (const float*)d_in[19];
  const float* v3b     = (const float*)d_in[20];
  const float* qkvW    = (const float*)d_in[21];
  const float* qkvB    = (const float*)d_in[22];
  const float* outW    = (const float*)d_in[23];
  const float* outb    = (const float*)d_in[24];
  const float* l1g     = (const float*)d_in[25];
  const float* l1b     = (const float*)d_in[26];
  const float* f1W     = (const float*)d_in[27];
  const float* f1b     = (const float*)d_in[28];
  const float* f2W     = (const float*)d_in[29];
  const float* f2b     = (const float*)d_in[30];
  const float* l2g     = (const float*)d_in[31];
  const float* l2b     = (const float*)d_in[32];
  const float* headW   = (const float*)d_in[33];
  const float* headB   = (const float*)d_in[34];
  float* dout = (float*)d_out;

  char* wsb = (char*)d_ws;
  size_t off = 0;
  auto nxt = [&](size_t bytes)->void*{
    void* p = wsb + off;
    off += (bytes + 255) & ~(size_t)255;
    return p;
  };
  u16*   h      = (u16*)  nxt((size_t)NODES*64*2);
  u16*   z      = (u16*)  nxt((size_t)NODES*64*2);
  u16*   u      = (u16*)  nxt((size_t)NODES*64*2);
  int*   rowptr = (int*)  nxt((size_t)(NODES+1)*4);
  int*   cursor = (int*)  nxt((size_t)NODES*4);
  int*   counts = (int*)  nxt((size_t)NODES*4);
  int*   bsums  = (int*)  nxt(64*4);
  int*   boffs  = (int*)  nxt(64*4);
  int*   esrc   = (int*)  nxt((size_t)EDGES*4);
  float* pooled = (float*)nxt((size_t)NG*64*4);
  float* tbuf   = (float*)nxt((size_t)NG*128*4);
  u16*   qkv0   = (u16*)  nxt((size_t)NG*384*2);
  u16*   qkv1   = (u16*)  nxt((size_t)NG*384*2);
  u16*   w1tg   = (u16*)  nxt((size_t)49152*2);
  u16*   w2tg   = (u16*)  nxt((size_t)49152*2);
  u16*   owt    = (u16*)  nxt((size_t)98304*2);
  u16*   f1t    = (u16*)  nxt((size_t)98304*2);
  u16*   f2t    = (u16*)  nxt((size_t)98304*2);
  u16*   qwt    = (u16*)  nxt((size_t)294912*2);
  u16*   qkvb[2] = { qkv0, qkv1 };

  const int* srcp = ei;
  const int* dstp = ei + EDGES;

  k_init   <<<391, 256, 0, stream>>>(counts, pooled, m1W, m2W, w1tg, w2tg,
                                     outW, f1W, f2W, qkvW, owt, f1t, f2t, qwt);
  k_hist   <<<4688, 256, 0, stream>>>(dstp, counts);
  k_scan1  <<<49, 256, 0, stream>>>(counts, rowptr, bsums);
  k_scan2  <<<1, 64, 0, stream>>>(bsums, boffs, 49);
  k_scan3  <<<391, 256, 0, stream>>>(rowptr, cursor, boffs);
  k_scatter<<<4688, 256, 0, stream>>>(srcp, dstp, cursor, esrc);
  k_enc    <<<391, 256, 0, stream>>>(x, encW, encb, ln_g, ln_b, h, z);

  for (int i = 0; i < 6; i++){
    int last = (i == 5);
    k_agg <<<6250, 256, 0, stream>>>((const u32*)z, (u32*)u, rowptr, esrc, tparam, i);
    k_mlpm<<<782, 256, 0, stream>>>(u, h, z, pooled, batch,
        w1tg + i*8192, w2tg + i*8192,
        m1b + i*128, mng + i*128, mnb + i*128,
        m2b + i*64,
        ln_g + (last ? 0 : (i+1)*64), ln_b + (last ? 0 : (i+1)*64), last);
  }

  k_pool2<<<NG, 128, 0, stream>>>(pooled, var_d, v1W, v1b, v2W, v2b, v3W, v3b,
                                  tbuf, qkv0, qkvW, qkvB);

  for (int i = 0; i < 6; i++){
    int last = (i == 5);
    k_attrow<<<NG, 256, 0, stream>>>(qkvb[i & 1], tbuf, qkvb[(i + 1) & 1],
        owt + i*16384, outb + i*128, l1g + i*128, l1b + i*128,
        f1t + i*16384, f1b + i*128, f2t + i*16384, f2b + i*128,
        l2g + i*128, l2b + i*128,
        qwt + (size_t)(last ? 0 : (i+1))*49152, qkvB + (last ? 0 : (i+1))*384,
        headW, headB, dout, last);
  }
}